// Round 5
// baseline (4284.780 us; speedup 1.0000x reference)
//
#include <hip/hip_runtime.h>
#include <hip/hip_bf16.h>

// ---- model constants ----
#define DIMQ 768
#define D_IN 1024
#define NQ 384
#define NBK 12
#define BATCH 2
#define LSEQ 1024
#define DI 1536
#define DS 16
#define DTR 48
#define NH 16
#define HD 48

typedef __attribute__((ext_vector_type(8))) short short8;
typedef __attribute__((ext_vector_type(4))) float f32x4;

#define GF_BIAS 1
#define GF_SOFTPLUS 2
#define EPI_BIAS 1
#define EPI_ADDT 2

#define LOG2E 1.4426950408889634f

__device__ __forceinline__ unsigned short f2bf(float f) {
    unsigned int u = __builtin_bit_cast(unsigned int, f);
    u = (u + 0x7FFFu + ((u >> 16) & 1u)) >> 16;
    return (unsigned short)u;
}
__device__ __forceinline__ float bf2f(unsigned short h) {
    unsigned int u = ((unsigned int)h) << 16;
    return __builtin_bit_cast(float, u);
}

__device__ __forceinline__ void gload_lds16(const void* g, void* l) {
    __builtin_amdgcn_global_load_lds(
        (const __attribute__((address_space(1))) void*)g,
        (__attribute__((address_space(3))) void*)l, 16, 0, 0);
}

// ---------------------------------------------------------------------------
// Weight conversion: fp32 -> bf16 hi/lo planes, with zero padding.
// ---------------------------------------------------------------------------
struct WTab {
    const float* src[10];
    long long dstOff[10];
    long long ps[10];
    int cum[10];
    int rows[10], cols[10], dcols[10];
    int n;
    int total;
};

__global__ void wconv_kernel(unsigned short* __restrict__ dst, WTab T)
{
    const int i = blockIdx.x * 256 + threadIdx.x;
    if (i >= T.total) return;
    int sI = 0;
    while (i >= T.cum[sI]) ++sI;
    const int e = i - (sI ? T.cum[sI - 1] : 0);
    const int dcols = T.dcols[sI];
    const int r = e / dcols;
    const int c = e - r * dcols;
    float v = 0.f;
    if (r < T.rows[sI] && c < T.cols[sI]) v = T.src[sI][(long long)r * T.cols[sI] + c];
    const unsigned short h = f2bf(v);
    const unsigned short l = f2bf(v - bf2f(h));
    dst[T.dstOff[sI] + e] = h;
    dst[T.dstOff[sI] + T.ps[sI] + e] = l;
}

// Per-layer block-weight conversion; grid = (28800, nLayers). One launch
// converts all 12 layers when the workspace allows (layerStride apart).
struct LTab {
    const float* src[7];
    long long srcStride[7], dstOff[7], ps[7];
    int rows[7], cols[7], dcols[7], cum[7];
};

__global__ __launch_bounds__(256)
void wconv_layers(unsigned short* __restrict__ dst, long long layerStride, int lBase, LTab T)
{
    const int e = blockIdx.x * 256 + threadIdx.x;   // < 7,372,800 exactly
    const int l = blockIdx.y + lBase;
    int sI = 0;
    while (e >= T.cum[sI]) ++sI;
    const int eo = e - (sI ? T.cum[sI - 1] : 0);
    const int dc = T.dcols[sI];
    const int r = eo / dc;
    const int c = eo - r * dc;
    float v = 0.f;
    if (r < T.rows[sI] && c < T.cols[sI])
        v = T.src[sI][(long long)l * T.srcStride[sI] + (long long)r * T.cols[sI] + c];
    const unsigned short h = f2bf(v);
    const unsigned short lo2 = f2bf(v - bf2f(h));
    unsigned short* d = dst + (long long)blockIdx.y * layerStride + T.dstOff[sI];
    d[eo] = h;
    d[T.ps[sI] + eo] = lo2;
}

// ---------------------------------------------------------------------------
// GEMM core (double-buffered): C[M,N] = A[M,K](fp32, split in-kernel)
//  * B[N,K]^T (bf16 hi/lo planes via global_load_lds DMA). Tile 64x128, BK=32.
// NOTE: intra-kernel cross-block reduce (atomic-counter fused split-K) was
// tried and costs a per-block buffer_wbl2 on multi-XCD CDNA -> 93us/dispatch.
// Kernel-boundary epilogue amortizes the L2 flush to once per dispatch.
// ---------------------------------------------------------------------------
__global__ __launch_bounds__(256, 3)
void gemm_direct(const float* __restrict__ Ag, const unsigned short* __restrict__ Bhl,
                 float* __restrict__ Cg, const float* __restrict__ biasg,
                 int M, int N, int K, int lda, int ldb, int ldc,
                 long long sA, long long sB, long long sC, long long sBias,
                 long long planeB, int flags)
{
    __shared__ __align__(16) unsigned short As[2][2][64][40];
    __shared__ __align__(16) unsigned short Bs[2][2][128][32];

    const int z = blockIdx.z;
    const float* A = Ag + (size_t)z * sA;
    const unsigned short* Bhi = Bhl + (size_t)z * sB;
    const unsigned short* Blo = Bhi + planeB;
    float* C = Cg + (size_t)z * sC;

    const int mBase = blockIdx.x * 64;
    const int nBase = blockIdx.y * 128;
    const int tid = threadIdx.x, lane = tid & 63, wave = tid >> 6;
    const int lm = lane & 15, lq = lane >> 4;
    const int wn = wave * 32;
    const int arow = tid >> 2, aq = tid & 3;
    const int brow = lane >> 2;
    const int bcol = (lane & 3) * 8;

    const int ktiles = (K + 31) >> 5;

    auto issueB = [&](int t, int buf) {
#pragma unroll
        for (int cc = 0; cc < 4; ++cc) {
            const int chunk = wave * 4 + cc;
            const int pl = chunk >> 3;
            const int r16 = chunk & 7;
            const unsigned short* bp = pl ? Blo : Bhi;
            const int n = nBase + r16 * 16 + brow;
            gload_lds16(bp + (size_t)n * ldb + t * 32 + bcol, &Bs[buf][pl][r16 * 16][0]);
        }
    };
    auto loadA = [&](int t, float* v) {
        const int col = t * 32 + aq * 8;
        const float* src = A + (size_t)(mBase + arow) * lda + col;
#pragma unroll
        for (int u = 0; u < 2; ++u) {
            float4 t4 = make_float4(0.f, 0.f, 0.f, 0.f);
            if (col + u * 4 < K) t4 = *(const float4*)(src + u * 4);
            v[u*4+0]=t4.x; v[u*4+1]=t4.y; v[u*4+2]=t4.z; v[u*4+3]=t4.w;
        }
    };
    auto writeA = [&](const float* v, int buf) {
        short8 ph, plv;
#pragma unroll
        for (int j = 0; j < 8; ++j) {
            unsigned short h = f2bf(v[j]);
            ph[j] = (short)h;
            plv[j] = (short)f2bf(v[j] - bf2f(h));
        }
        *(short8*)&As[buf][0][arow][aq * 8] = ph;
        *(short8*)&As[buf][1][arow][aq * 8] = plv;
    };

    float av[8];
    issueB(0, 0);
    loadA(0, av);
    writeA(av, 0);

    f32x4 acc[4][2] = {};
    for (int t = 0; t < ktiles; ++t) {
        const int buf = t & 1;
        __syncthreads();
        const bool more = (t + 1) < ktiles;
        if (more) { issueB(t + 1, buf ^ 1); loadA(t + 1, av); }
        short8 ah[4], al[4], bh[2], bl[2];
#pragma unroll
        for (int i = 0; i < 4; ++i) {
            ah[i] = *(const short8*)&As[buf][0][16*i + lm][lq * 8];
            al[i] = *(const short8*)&As[buf][1][16*i + lm][lq * 8];
        }
#pragma unroll
        for (int j = 0; j < 2; ++j) {
            bh[j] = *(const short8*)&Bs[buf][0][wn + 16*j + lm][lq * 8];
            bl[j] = *(const short8*)&Bs[buf][1][wn + 16*j + lm][lq * 8];
        }
#pragma unroll
        for (int i = 0; i < 4; ++i)
#pragma unroll
            for (int j = 0; j < 2; ++j) {
                acc[i][j] = __builtin_amdgcn_mfma_f32_16x16x32_bf16(ah[i], bh[j], acc[i][j], 0, 0, 0);
                acc[i][j] = __builtin_amdgcn_mfma_f32_16x16x32_bf16(ah[i], bl[j], acc[i][j], 0, 0, 0);
                acc[i][j] = __builtin_amdgcn_mfma_f32_16x16x32_bf16(al[i], bh[j], acc[i][j], 0, 0, 0);
            }
        if (more) writeA(av, buf ^ 1);
    }

#pragma unroll
    for (int i = 0; i < 4; ++i)
#pragma unroll
        for (int j = 0; j < 2; ++j)
#pragma unroll
            for (int r = 0; r < 4; ++r) {
                const int m = mBase + i*16 + lq*4 + r;
                const int n = nBase + wn + j*16 + lm;
                float v = acc[i][j][r];
                if (flags & GF_BIAS)     v += biasg[(size_t)z * sBias + n];
                if (flags & GF_SOFTPLUS) v = (v > 20.f) ? v : log1pf(expf(v));
                C[(size_t)m * ldc + n] = v;
            }
}

// Split-K variant (double-buffered): grid.z = Z*S; partials Cp[(z*S+s)][M][ldP].
// kLen must be a multiple of 32.
__global__ __launch_bounds__(256, 3)
void gemm_splitk(const float* __restrict__ Ag, const unsigned short* __restrict__ Bhl,
                 float* __restrict__ Cp,
                 int M, int kLen, int S, int lda, int ldb, int ldP,
                 long long sA, long long sB, long long planeB)
{
    __shared__ __align__(16) unsigned short As[2][2][64][40];
    __shared__ __align__(16) unsigned short Bs[2][2][128][32];

    const int bz = blockIdx.z;
    const int s = bz % S, z = bz / S;
    const int kOff = s * kLen;
    const float* A = Ag + (size_t)z * sA;
    const unsigned short* Bhi = Bhl + (size_t)z * sB;
    const unsigned short* Blo = Bhi + planeB;

    const int mBase = blockIdx.x * 64;
    const int nBase = blockIdx.y * 128;
    const int tid = threadIdx.x, lane = tid & 63, wave = tid >> 6;
    const int lm = lane & 15, lq = lane >> 4;
    const int wn = wave * 32;
    const int arow = tid >> 2, aq = tid & 3;
    const int brow = lane >> 2;
    const int bcol = (lane & 3) * 8;

    const int ktiles = kLen >> 5;

    auto issueB = [&](int t, int buf) {
#pragma unroll
        for (int cc = 0; cc < 4; ++cc) {
            const int chunk = wave * 4 + cc;
            const int pl = chunk >> 3;
            const int r16 = chunk & 7;
            const unsigned short* bp = pl ? Blo : Bhi;
            const int n = nBase + r16 * 16 + brow;
            gload_lds16(bp + (size_t)n * ldb + kOff + t * 32 + bcol, &Bs[buf][pl][r16 * 16][0]);
        }
    };
    auto loadA = [&](int t, float* v) {
        const float* src = A + (size_t)(mBase + arow) * lda + kOff + t * 32 + aq * 8;
#pragma unroll
        for (int u = 0; u < 2; ++u) {
            const float4 t4 = *(const float4*)(src + u * 4);
            v[u*4+0]=t4.x; v[u*4+1]=t4.y; v[u*4+2]=t4.z; v[u*4+3]=t4.w;
        }
    };
    auto writeA = [&](const float* v, int buf) {
        short8 ph, plv;
#pragma unroll
        for (int j = 0; j < 8; ++j) {
            unsigned short h = f2bf(v[j]);
            ph[j] = (short)h;
            plv[j] = (short)f2bf(v[j] - bf2f(h));
        }
        *(short8*)&As[buf][0][arow][aq * 8] = ph;
        *(short8*)&As[buf][1][arow][aq * 8] = plv;
    };

    float av[8];
    issueB(0, 0);
    loadA(0, av);
    writeA(av, 0);

    f32x4 acc[4][2] = {};
    for (int t = 0; t < ktiles; ++t) {
        const int buf = t & 1;
        __syncthreads();
        const bool more = (t + 1) < ktiles;
        if (more) { issueB(t + 1, buf ^ 1); loadA(t + 1, av); }
        short8 ah[4], al[4], bh[2], bl[2];
#pragma unroll
        for (int i = 0; i < 4; ++i) {
            ah[i] = *(const short8*)&As[buf][0][16*i + lm][lq * 8];
            al[i] = *(const short8*)&As[buf][1][16*i + lm][lq * 8];
        }
#pragma unroll
        for (int j = 0; j < 2; ++j) {
            bh[j] = *(const short8*)&Bs[buf][0][wn + 16*j + lm][lq * 8];
            bl[j] = *(const short8*)&Bs[buf][1][wn + 16*j + lm][lq * 8];
        }
#pragma unroll
        for (int i = 0; i < 4; ++i)
#pragma unroll
            for (int j = 0; j < 2; ++j) {
                acc[i][j] = __builtin_amdgcn_mfma_f32_16x16x32_bf16(ah[i], bh[j], acc[i][j], 0, 0, 0);
                acc[i][j] = __builtin_amdgcn_mfma_f32_16x16x32_bf16(ah[i], bl[j], acc[i][j], 0, 0, 0);
                acc[i][j] = __builtin_amdgcn_mfma_f32_16x16x32_bf16(al[i], bh[j], acc[i][j], 0, 0, 0);
            }
        if (more) writeA(av, buf ^ 1);
    }

    float* Cb = Cp + (size_t)bz * M * ldP;
#pragma unroll
    for (int i = 0; i < 4; ++i)
#pragma unroll
        for (int j = 0; j < 2; ++j)
#pragma unroll
            for (int r = 0; r < 4; ++r) {
                const int m = mBase + i*16 + lq*4 + r;
                const int n = nBase + wn + j*16 + lm;
                Cb[(size_t)m * ldP + n] = acc[i][j][r];
            }
}

// Reduce partials + bias/residual, write fp32 out.
__global__ void epi_kernel(const float* __restrict__ Cp, float* __restrict__ outF,
                           const float* __restrict__ bias, const float* __restrict__ addT,
                           int Z, int S, int M, int N, int ldP, int ldOut,
                           long long sOutZ, long long sBiasZ, int ldAdd, int flags)
{
    const int n4 = N >> 2;
    const int idx = blockIdx.x * 256 + threadIdx.x;
    if (idx >= Z * M * n4) return;
    const int c4 = idx % n4;
    const int rem = idx / n4;
    const int m = rem % M;
    const int z = rem / M;
    const int n = c4 * 4;
    const float* base = Cp + ((size_t)z * S * M + m) * ldP + n;
    float4 v = *(const float4*)base;
    for (int s = 1; s < S; ++s) {
        const float4 u = *(const float4*)(base + (size_t)s * M * ldP);
        v.x += u.x; v.y += u.y; v.z += u.z; v.w += u.w;
    }
    if (flags & EPI_BIAS) {
        const float4 b4 = *(const float4*)(bias + (size_t)z * sBiasZ + n);
        v.x += b4.x; v.y += b4.y; v.z += b4.z; v.w += b4.w;
    }
    if (flags & EPI_ADDT) {
        const float4 a4 = *(const float4*)(addT + (size_t)m * ldAdd + n);
        v.x += a4.x; v.y += a4.y; v.z += a4.z; v.w += a4.w;
    }
    *(float4*)(outF + (size_t)z * sOutZ + (size_t)m * ldOut + n) = v;
}

// Reduce partials + bias, then LayerNorm the 768-wide row, write xn.
// One block per row (256 thr x 3 cols). Fuses the next layer's input LN
// into the cross-proj epilogue (xbuf round-trip eliminated).
__global__ __launch_bounds__(256)
void epi_ln_kernel(const float* __restrict__ Cp, float* __restrict__ outF,
                   const float* __restrict__ bias,
                   const float* __restrict__ g, const float* __restrict__ b,
                   int S, int M, int ldP)
{
    const int m = blockIdx.x;
    const int tid = threadIdx.x;
    __shared__ float red[8];
    float v[3];
    float s = 0.f, s2 = 0.f;
#pragma unroll
    for (int j = 0; j < 3; ++j) {
        const int n = tid + j * 256;
        const float* pp = Cp + (size_t)m * ldP + n;
        float x = pp[0];
        for (int q = 1; q < S; ++q) x += pp[(size_t)q * M * ldP];
        x += bias[n];
        v[j] = x; s += x; s2 += x * x;
    }
#pragma unroll
    for (int o = 32; o; o >>= 1) { s += __shfl_xor(s, o); s2 += __shfl_xor(s2, o); }
    const int wv = tid >> 6;
    if ((tid & 63) == 0) { red[wv] = s; red[4 + wv] = s2; }
    __syncthreads();
    s  = red[0] + red[1] + red[2] + red[3];
    s2 = red[4] + red[5] + red[6] + red[7];
    const float mean = s * (1.f/768.f);
    const float var  = s2 * (1.f/768.f) - mean * mean;
    const float inv  = rsqrtf(var + 1e-5f);
#pragma unroll
    for (int j = 0; j < 3; ++j) {
        const int n = tid + j * 256;
        outF[(size_t)m * DIMQ + n] = (v[j] - mean) * inv * g[n] + b[n];
    }
}

// ---------------------------------------------------------------------------
// LayerNorm over last dim 768. One wave per row. srcMod broadcasts src rows.
// ---------------------------------------------------------------------------
__global__ void ln_kernel(const float* __restrict__ in, float* __restrict__ out,
                          const float* __restrict__ g, const float* __restrict__ b,
                          int rows, int srcMod)
{
    const int row = blockIdx.x * 4 + (threadIdx.x >> 6);
    const int lane = threadIdx.x & 63;
    if (row >= rows) return;
    const float* p = in + (size_t)(row % srcMod) * DIMQ;
    float v[12], s = 0.f, s2 = 0.f;
#pragma unroll
    for (int j = 0; j < 12; ++j) {
        v[j] = p[j*64 + lane];
        s += v[j];
        s2 += v[j]*v[j];
    }
#pragma unroll
    for (int o = 32; o; o >>= 1) { s += __shfl_xor(s, o); s2 += __shfl_xor(s2, o); }
    const float mean = s * (1.f/768.f);
    const float var  = s2 * (1.f/768.f) - mean*mean;
    const float inv  = rsqrtf(var + 1e-5f);
    float* q = out + (size_t)row * DIMQ;
#pragma unroll
    for (int j = 0; j < 12; ++j) {
        const int c = j*64 + lane;
        q[c] = (v[j] - mean) * inv * g[c] + b[c];
    }
}

// ---------------------------------------------------------------------------
// Depthwise causal conv1d (DC=4) + silu.
// ---------------------------------------------------------------------------
__global__ void conv_kernel(const float* __restrict__ xz, float* __restrict__ xc,
                            const float* __restrict__ cw, const float* __restrict__ cb,
                            int Bn, int L, int instShift)
{
    const int idx = blockIdx.x * 256 + threadIdx.x;
    const int total = Bn * L * (DI/4);
    if (idx >= total) return;
    const int d4 = idx % (DI/4);
    const int t  = (idx / (DI/4)) % L;
    const int b  = idx / (L * (DI/4));
    const int inst = b >> instShift;
    const int d = d4 * 4;
    const float* base = xz + (size_t)(b * L) * 3072 + d;
    const float4 w0 = *(const float4*)(cw + (size_t)(inst*DI + d + 0) * 4);
    const float4 w1 = *(const float4*)(cw + (size_t)(inst*DI + d + 1) * 4);
    const float4 w2 = *(const float4*)(cw + (size_t)(inst*DI + d + 2) * 4);
    const float4 w3 = *(const float4*)(cw + (size_t)(inst*DI + d + 3) * 4);
    float4 acc = *(const float4*)(cb + (size_t)inst*DI + d);
    float4 xv[4];
#pragma unroll
    for (int j = 0; j < 4; ++j) {
        const int tt = t - 3 + j;
        xv[j] = (tt >= 0) ? *(const float4*)(base + (size_t)tt * 3072) : make_float4(0,0,0,0);
    }
    acc.x += xv[0].x*w0.x + xv[1].x*w0.y + xv[2].x*w0.z + xv[3].x*w0.w;
    acc.y += xv[0].y*w1.x + xv[1].y*w1.y + xv[2].y*w1.z + xv[3].y*w1.w;
    acc.z += xv[0].z*w2.x + xv[1].z*w2.y + xv[2].z*w2.z + xv[3].z*w2.w;
    acc.w += xv[0].w*w3.x + xv[1].w*w3.y + xv[2].w*w3.z + xv[3].w*w3.w;
    float4 o;
    o.x = acc.x / (1.f + expf(-acc.x));
    o.y = acc.y / (1.f + expf(-acc.y));
    o.z = acc.z / (1.f + expf(-acc.z));
    o.w = acc.w / (1.f + expf(-acc.w));
    *(float4*)(xc + (size_t)(b * L + t) * DI + d) = o;
}

// ---------------------------------------------------------------------------
// Chunked selective scan (2 passes; inter-chunk carry recurrence is inlined
// into pass 3 -- each chunk-c block replays the p2 loop over chunks < c,
// bit-identical to the old separate scan_p2 kernel).
// ---------------------------------------------------------------------------
__global__ __launch_bounds__(256)
void scan_p1(const float* __restrict__ dt, const float* __restrict__ dbl,
             const float* __restrict__ xc, const float* __restrict__ A_log,
             float* __restrict__ hend, float* __restrict__ sumdt,
             int L, int CL, int Bn, int instShift)
{
    const int d = blockIdx.x * 256 + threadIdx.x;
    const int b = blockIdx.y;
    const int c = blockIdx.z;
    const int inst = b >> instShift;
    const float* ap = A_log + ((size_t)inst * DI + d) * DS;
    float A2[16];
#pragma unroll
    for (int s = 0; s < 16; ++s) A2[s] = -expf(ap[s]) * LOG2E;
    float h[16] = {};
    float sd = 0.f;
    const int t0 = c * CL;
    const size_t rowbase = (size_t)b * L;
    for (int t = t0; t < t0 + CL; ++t) {
        const size_t row = rowbase + t;
        const float dtv = dt[row * DI + d];
        const float xcv = xc[row * DI + d];
        float Bv[16];
        *(float4*)(Bv + 0)  = *(const float4*)(dbl + row * 80 + 48);
        *(float4*)(Bv + 4)  = *(const float4*)(dbl + row * 80 + 52);
        *(float4*)(Bv + 8)  = *(const float4*)(dbl + row * 80 + 56);
        *(float4*)(Bv + 12) = *(const float4*)(dbl + row * 80 + 60);
        sd += dtv;
        const float bx = dtv * xcv;
#pragma unroll
        for (int s = 0; s < 16; ++s)
            h[s] = exp2f(dtv * A2[s]) * h[s] + bx * Bv[s];
    }
    float* hp = hend + (((size_t)c * Bn + b) * DI + d) * DS;
#pragma unroll
    for (int s = 0; s < 16; s += 4)
        *(float4*)(hp + s) = make_float4(h[s], h[s+1], h[s+2], h[s+3]);
    sumdt[((size_t)c * Bn + b) * DI + d] = sd;
}

__global__ __launch_bounds__(256)
void scan_p3f(const float* __restrict__ dt, const float* __restrict__ dbl,
              const float* __restrict__ xc, const float* __restrict__ xz,
              const float* __restrict__ A_log, const float* __restrict__ Dp,
              const float* __restrict__ hend, const float* __restrict__ sumdt,
              float* __restrict__ y,
              int L, int CL, int Bn, int instShift)
{
    const int d = blockIdx.x * 256 + threadIdx.x;
    const int b = blockIdx.y;
    const int c = blockIdx.z;
    const int inst = b >> instShift;
    const float* ap = A_log + ((size_t)inst * DI + d) * DS;
    float A2[16];
#pragma unroll
    for (int s = 0; s < 16; ++s) A2[s] = -expf(ap[s]) * LOG2E;
    const float Dd = Dp[(size_t)inst * DI + d];

    // inlined inter-chunk carry (old scan_p2), chunks 0..c-1 ascending
    float h[16] = {};
    for (int cp = 0; cp < c; ++cp) {
        const float sd = sumdt[((size_t)cp * Bn + b) * DI + d];
        const float* hp = hend + (((size_t)cp * Bn + b) * DI + d) * DS;
        float he[16];
#pragma unroll
        for (int s = 0; s < 16; s += 4) {
            const float4 t4 = *(const float4*)(hp + s);
            he[s] = t4.x; he[s+1] = t4.y; he[s+2] = t4.z; he[s+3] = t4.w;
        }
#pragma unroll
        for (int s = 0; s < 16; ++s)
            h[s] = exp2f(A2[s] * sd) * h[s] + he[s];
    }

    const int t0 = c * CL;
    const size_t rowbase = (size_t)b * L;
    for (int t = t0; t < t0 + CL; ++t) {
        const size_t row = rowbase + t;
        const float dtv = dt[row * DI + d];
        const float xcv = xc[row * DI + d];
        const float zv  = xz[row * 3072 + DI + d];
        float Bv[16], Cv[16];
        *(float4*)(Bv + 0)  = *(const float4*)(dbl + row * 80 + 48);
        *(float4*)(Bv + 4)  = *(const float4*)(dbl + row * 80 + 52);
        *(float4*)(Bv + 8)  = *(const float4*)(dbl + row * 80 + 56);
        *(float4*)(Bv + 12) = *(const float4*)(dbl + row * 80 + 60);
        *(float4*)(Cv + 0)  = *(const float4*)(dbl + row * 80 + 64);
        *(float4*)(Cv + 4)  = *(const float4*)(dbl + row * 80 + 68);
        *(float4*)(Cv + 8)  = *(const float4*)(dbl + row * 80 + 72);
        *(float4*)(Cv + 12) = *(const float4*)(dbl + row * 80 + 76);
        const float bx = dtv * xcv;
#pragma unroll
        for (int s = 0; s < 16; ++s)
            h[s] = exp2f(dtv * A2[s]) * h[s] + bx * Bv[s];
        float p0 = 0.f, p1 = 0.f, p2 = 0.f, p3 = 0.f;
#pragma unroll
        for (int s = 0; s < 4; ++s) {
            p0 += h[s]      * Cv[s];
            p1 += h[s + 4]  * Cv[s + 4];
            p2 += h[s + 8]  * Cv[s + 8];
            p3 += h[s + 12] * Cv[s + 12];
        }
        const float p = (p0 + p1) + (p2 + p3);
        y[row * DI + d] = (p + Dd * xcv) * (zv / (1.f + expf(-zv)));
    }
}

// ---------------------------------------------------------------------------
// Local-window cross attention (2-3 keys/query). Reads q directly from the
// split-K partial planes (+bias): the q epilogue kernel is fused in.
// ---------------------------------------------------------------------------
__global__ void attn_kernel(const float* __restrict__ qP, const float* __restrict__ qBias,
                            const float* __restrict__ kv, float* __restrict__ o,
                            int S, int ldP)
{
    const int bi = blockIdx.x;
    const int b = bi / NQ, i = bi % NQ;
    const int tid = threadIdx.x;
    const int h = tid >> 2, r = tid & 3;
    int start, len;
    if (i < 256) { start = 3*i; len = 3; } else { start = 2*i + 256; len = 2; }
    const int col0 = h*48 + r*12;
    float qv[12];
#pragma unroll
    for (int u = 0; u < 12; ++u) {
        const int n = col0 + u;
        float x = qP[(size_t)bi * ldP + n];
        for (int s = 1; s < S; ++s) x += qP[((size_t)s * 768 + bi) * ldP + n];
        qv[u] = x + qBias[n];
    }
    float s[3] = {-1e30f, -1e30f, -1e30f};
    for (int j = 0; j < len; ++j) {
        const float* kp = kv + (size_t)(b*LSEQ + start + j) * 1536 + col0;
        float p = 0.f;
#pragma unroll
        for (int u = 0; u < 12; ++u) p += qv[u] * kp[u];
        p += __shfl_xor(p, 1);
        p += __shfl_xor(p, 2);
        s[j] = p * 0.14433756729740644f;
    }
    const float mx = fmaxf(s[0], fmaxf(s[1], s[2]));
    float e[3];
    e[0] = expf(s[0]-mx); e[1] = expf(s[1]-mx); e[2] = expf(s[2]-mx);
    const float inv = 1.f / (e[0] + e[1] + e[2]);
    float ov[12] = {};
    for (int j = 0; j < len; ++j) {
        const float w = e[j] * inv;
        const float* vp = kv + (size_t)(b*LSEQ + start + j) * 1536 + 768 + col0;
#pragma unroll
        for (int u = 0; u < 12; ++u) ov[u] += w * vp[u];
    }
    float* op = o + (size_t)bi * DIMQ + col0;
#pragma unroll
    for (int u = 0; u < 12; ++u) op[u] = ov[u];
}

// ---------------------------------------------------------------------------
// small utility kernels
// ---------------------------------------------------------------------------
__global__ void flip_kernel(float* __restrict__ X2)
{
    const int idx = blockIdx.x * 256 + threadIdx.x;
    if (idx >= 2*1024*192) return;
    const int d4 = idx % 192;
    const int t  = (idx / 192) % 1024;
    const int b  = idx / (192 * 1024);
    const size_t dst = ((size_t)((2+b)*1024 + t)) * DIMQ + d4*4;
    const size_t src = ((size_t)(b*1024 + (1023 - t))) * DIMQ + d4*4;
    *(float4*)(X2 + dst) = *(const float4*)(X2 + src);
}

__global__ void combine_kernel(const float* __restrict__ oe, const float* __restrict__ feats,
                               float* __restrict__ c)
{
    const int idx = blockIdx.x * 256 + threadIdx.x;
    if (idx >= 2*1024*192) return;
    const int d4 = idx % 192;
    const int t  = (idx / 192) % 1024;
    const int b  = idx / (192 * 1024);
    const size_t fw = ((size_t)(b*1024 + t)) * DIMQ + d4*4;
    const size_t bw = ((size_t)((2+b)*1024 + (1023 - t))) * DIMQ + d4*4;
    const float4 a = *(const float4*)(oe + fw);
    const float4 bb = *(const float4*)(oe + bw);
    const float4 f = *(const float4*)(feats + fw);
    float4 o;
    o.x = a.x + bb.x + f.x; o.y = a.y + bb.y + f.y;
    o.z = a.z + bb.z + f.z; o.w = a.w + bb.w + f.w;
    *(float4*)(c + fw) = o;
}

// ---------------------------------------------------------------------------
extern "C" void kernel_launch(void* const* d_in, const int* in_sizes, int n_in,
                              void* d_out, int out_size, void* d_ws, size_t ws_size,
                              hipStream_t stream) {
    const float* img_emb  = (const float*)d_in[0];
    const float* queries  = (const float*)d_in[1];
    const float* vis_w    = (const float*)d_in[2];
    const float* vis_b    = (const float*)d_in[3];
    const float* lnv_g    = (const float*)d_in[4];
    const float* lnv_b    = (const float*)d_in[5];
    const float* m_in_w   = (const float*)d_in[6];
    const float* m_conv_w = (const float*)d_in[7];
    const float* m_conv_b = (const float*)d_in[8];
    const float* m_xp_w   = (const float*)d_in[9];
    const float* m_dt_w   = (const float*)d_in[10];
    const float* m_dt_b   = (const float*)d_in[11];
    const float* m_A_log  = (const float*)d_in[12];
    const float* m_D      = (const float*)d_in[13];
    const float* m_out_w  = (const float*)d_in[14];
    const float* sn_g     = (const float*)d_in[15];
    const float* sn_b     = (const float*)d_in[16];
    const float* a_in_w   = (const float*)d_in[17];
    const float* a_in_b   = (const float*)d_in[18];
    const float* a_out_w  = (const float*)d_in[19];
    const float* a_out_b  = (const float*)d_in[20];
    const float* cr_w     = (const float*)d_in[21];
    const float* cr_b     = (const float*)d_in[22];
    float* out = (float*)d_out;

    float* ws = (float*)d_ws;
    auto alloc = [&](size_t n) { float* p = ws; ws += n; return p; };
    float* X2   = alloc((size_t)4096*768);
    float* xzb  = alloc((size_t)4096*3072);
    float* xcb  = alloc((size_t)4096*1536);
    float* dblb = alloc((size_t)4096*80);
    float* dtb  = alloc((size_t)4096*1536);
    float* yb   = alloc((size_t)4096*1536);
    float* oe   = alloc((size_t)4096*768);     // also scan temps (hend+sumdt)
    float* cbuf = alloc((size_t)2048*768);
    float* xn   = alloc((size_t)768*768);
    float* x1s  = alloc((size_t)768*1536);
    float* ob   = alloc((size_t)768*768);
    float* Cp   = alloc((size_t)2359296);      // split-K partials (dedicated)
    unsigned short* wenc = (unsigned short*)alloc((size_t)16908288/2);

    const long long LAYER_USH = 14745600;      // ushorts per converted layer
    const size_t usedFloats = (size_t)(ws - (float*)d_ws);
    const size_t needFull = (usedFloats + (size_t)12 * (LAYER_USH/2)) * 4;
    const bool bigW = ws_size >= needFull;
    unsigned short* wlayAll = (unsigned short*)ws;   // 12 layers (bigW) or 1 (fallback)

    // batched-kv buffer sits after the 12 converted layers (only if bigW)
    const size_t kvFloats = (size_t)12 * 2048 * 1536;
    const size_t needKV = needFull + kvFloats * 4;
    const bool kvHoist = bigW && ws_size >= needKV;
    float* kvAll = (float*)(wlayAll + (size_t)12 * LAYER_USH);

    const long long P_VIS = 768LL*1024;
    const long long P_IN  = 3072LL*768;
    const long long P_XP  = 128LL*1536;
    const long long P_DT  = 1536LL*64;
    const long long P_OUT = 768LL*1536;
    const long long P_AIN = 2304LL*768;
    const long long P_AOUT= 768LL*768;
    const long long P_CR  = 768LL*1536;
    const long long off_vis   = 0;
    const long long off_encIn = 2*P_VIS;
    const long long off_encXp = off_encIn + 4*P_IN;
    const long long off_encDt = off_encXp + 4*P_XP;
    const long long off_encOut= off_encDt + 4*P_DT;
    const long long off_in  = 0;
    const long long off_xp  = 2*P_IN;
    const long long off_dt  = off_xp + 2*P_XP;
    const long long off_out = off_dt + 2*P_DT;
    const long long off_aIn = off_out + 2*P_OUT;
    const long long off_aOut= off_aIn + 2*P_AIN;
    const long long off_cr  = off_aOut + 2*P_AOUT;

    auto addSeg = [](WTab& T, const float* src, int rows, int cols, int drows, int dcols,
                     long long dstOff) {
        const int k = T.n;
        T.src[k] = src; T.rows[k] = rows; T.cols[k] = cols; T.dcols[k] = dcols;
        T.ps[k] = (long long)drows * dcols;
        T.dstOff[k] = dstOff;
        T.total += drows * dcols;
        T.cum[k] = T.total;
        T.n = k + 1;
    };

    auto GD = [&](const float* A, const unsigned short* Bhl, long long planeB,
                  float* C, const float* bias,
                  int M, int N, int K, int lda, int ldb, int ldc,
                  long long sA, long long sB, long long sC, long long sBias,
                  int Z, int flags) {
        dim3 grid(M/64, N/128, Z);
        gemm_direct<<<grid, 256, 0, stream>>>(A, Bhl, C, bias, M, N, K, lda, ldb, ldc,
                                              sA, sB, sC, sBias, planeB, flags);
    };
    auto GS = [&](const float* A, const unsigned short* Bhl, long long planeB,
                  int M, int Ntile, int kLen, int S, int lda, int ldb, int ldP,
                  long long sA, long long sB, int Z) {
        dim3 grid(M/64, Ntile/128, Z*S);
        gemm_splitk<<<grid, 256, 0, stream>>>(A, Bhl, Cp, M, kLen, S, lda, ldb, ldP,
                                              sA, sB, planeB);
    };
    auto EPI = [&](float* outF, const float* bias, const float* addT,
                   int Z, int S, int M, int N, int ldP, int ldOut,
                   long long sOutZ, long long sBiasZ, int ldAdd, int flags) {
        const int total = Z * M * (N/4);
        epi_kernel<<<(total+255)/256, 256, 0, stream>>>(Cp, outF, bias, addT, Z, S, M, N,
                                                        ldP, ldOut, sOutZ, sBiasZ, ldAdd, flags);
    };

    // ==== encoder weight conversion ====
    {
        WTab T = {}; T.n = 0; T.total = 0;
        addSeg(T, vis_w, 768, 1024, 768, 1024, off_vis);
        addSeg(T, m_in_w,               3072, 768, 3072, 768, off_encIn);
        addSeg(T, m_in_w + 3072*768,    3072, 768, 3072, 768, off_encIn + 2*P_IN);
        addSeg(T, m_xp_w,               80, 1536, 128, 1536, off_encXp);
        addSeg(T, m_xp_w + 80*1536,     80, 1536, 128, 1536, off_encXp + 2*P_XP);
        addSeg(T, m_dt_w,               1536, 48, 1536, 64, off_encDt);
        addSeg(T, m_dt_w + 1536*48,     1536, 48, 1536, 64, off_encDt + 2*P_DT);
        addSeg(T, m_out_w,              768, 1536, 768, 1536, off_encOut);
        addSeg(T, m_out_w + 768*1536,   768, 1536, 768, 1536, off_encOut + 2*P_OUT);
        wconv_kernel<<<(T.total+255)/256, 256, 0, stream>>>(wenc, T);
    }

    // ==== layer weight conversion table (mamba srcs pre-offset by +2 instances) ====
    LTab LT = {};
    {
        auto seg = [&](int k, const float* src, long long srcStride, int rows, int cols,
                       int drows, int dcols, long long dstOff) {
            LT.src[k] = src; LT.srcStride[k] = srcStride;
            LT.rows[k] = rows; LT.cols[k] = cols; LT.dcols[k] = dcols;
            LT.ps[k] = (long long)drows * dcols; LT.dstOff[k] = dstOff;
            LT.cum[k] = (k ? LT.cum[k-1] : 0) + drows * dcols;
        };
        seg(0, m_in_w  + (size_t)2*3072*768, 3072LL*768, 3072, 768, 3072, 768, off_in);
        seg(1, m_xp_w  + (size_t)2*80*1536,  80LL*1536,  80, 1536, 128, 1536, off_xp);
        seg(2, m_dt_w  + (size_t)2*1536*48,  1536LL*48,  1536, 48, 1536, 64, off_dt);
        seg(3, m_out_w + (size_t)2*768*1536, 768LL*1536, 768, 1536, 768, 1536, off_out);
        seg(4, a_in_w,  2304LL*768, 2304, 768, 2304, 768, off_aIn);
        seg(5, a_out_w, 768LL*768,  768, 768, 768, 768, off_aOut);
        seg(6, cr_w,    768LL*1536, 768, 1536, 768, 1536, off_cr);
    }
    if (bigW)
        wconv_layers<<<dim3(28800, 12), 256, 0, stream>>>(wlayAll, LAYER_USH, 0, LT);

    // ==== vision proj + LN + stacked feats ====
    GD(img_emb, wenc + off_vis, P_VIS, oe, vis_b,
       2048, 768, 1024, 1024, 1024, 768, 0,0,0,0, 1, GF_BIAS);
    ln_kernel<<<512, 256, 0, stream>>>(oe, X2, lnv_g, lnv_b, 2048, 2048);
    flip_kernel<<<(2*1024*192 + 255)/256, 256, 0, stream>>>(X2);

    // ==== encoder mambas (fwd + bwd via Z=2) ====
    GD(X2, wenc + off_encIn, P_IN, xzb, nullptr,
       2048, 3072, 768, 768, 768, 3072, 2048LL*768, 2*P_IN, 2048LL*3072, 0, 2, 0);
    conv_kernel<<<(4*1024*384 + 255)/256, 256, 0, stream>>>(xzb, xcb, m_conv_w, m_conv_b, 4, 1024, 1);
    GS(xcb, wenc + off_encXp, P_XP, 2048, 128, 384, 4, 1536, 1536, 128,
       2048LL*1536, 2*P_XP, 2);
    EPI(dblb, nullptr, nullptr, 2, 4, 2048, 80, 128, 80, 2048LL*80, 0, 0, 0);
    GD(dblb, wenc + off_encDt, P_DT, dtb, m_dt_b,
       2048, 1536, 48, 80, 64, 1536, 2048LL*80, 2*P_DT, 2048LL*1536, 1536, 2,
       GF_BIAS | GF_SOFTPLUS);
    {
        const int NC = 16, CL = 64;
        float* hend   = oe;                         // 1,572,864 floats
        float* sumdt  = oe + (size_t)NC*4*DI*DS;    // +98,304 (total < oe size)
        scan_p1<<<dim3(6, 4, NC), 256, 0, stream>>>(dtb, dblb, xcb, m_A_log, hend, sumdt, 1024, CL, 4, 1);
        scan_p3f<<<dim3(6, 4, NC), 256, 0, stream>>>(dtb, dblb, xcb, xzb, m_A_log, m_D,
                                                     hend, sumdt, yb, 1024, CL, 4, 1);
    }
    GD(yb, wenc + off_encOut, P_OUT, oe, nullptr,
       2048, 768, 1536, 1536, 1536, 768, 2048LL*1536, 2*P_OUT, 2048LL*768, 0, 2, 0);
    combine_kernel<<<(2*1024*192 + 255)/256, 256, 0, stream>>>(oe, X2, cbuf);

    // ==== batched k/v projection for ALL layers (input cbuf is layer-invariant) ====
    if (kvHoist)
        GD(cbuf, wlayAll + off_aIn + 768LL*768, P_AIN, kvAll, a_in_b + 768,
           2048, 1536, 768, 768, 768, 1536,
           0, LAYER_USH, 2048LL*1536, 2304, 12, GF_BIAS);

    // ==== initial LN (broadcast queries, layer-0 norm params) ====
    ln_kernel<<<192, 256, 0, stream>>>(queries, xn, sn_g, sn_b, 768, 384);

    // ==== 12 blocks ====
    for (int l = 0; l < NBK; ++l) {
        const int li = l + 2;
        const unsigned short* wl = bigW ? wlayAll + (size_t)l * LAYER_USH : wlayAll;
        if (!bigW)
            wconv_layers<<<dim3(28800, 1), 256, 0, stream>>>((unsigned short*)wlayAll, LAYER_USH, l, LT);

        GD(xn, wl + off_in, P_IN, xzb, nullptr,
           768, 3072, 768, 768, 768, 3072, 0,0,0,0, 1, 0);
        conv_kernel<<<(2*NQ*384 + 255)/256, 256, 0, stream>>>(
            xzb, xcb, m_conv_w + (size_t)li*DI*4, m_conv_b + (size_t)li*DI, 2, NQ, 8);
        GS(xcb, wl + off_xp, P_XP, 768, 128, 96, 16, 1536, 1536, 128, 0, 0, 1);
        EPI(dblb, nullptr, nullptr, 1, 16, 768, 80, 128, 80, 0, 0, 0, 0);
        GD(dblb, wl + off_dt, P_DT, dtb, m_dt_b + (size_t)li*1536,
           768, 1536, 48, 80, 64, 1536, 0,0,0,0, 1, GF_BIAS | GF_SOFTPLUS);
        {
            const int NC = 24, CL = 16;
            const float* Ap = m_A_log + (size_t)li*DI*DS;
            float* hend   = oe;                          // 1,179,648
            float* sumdt  = oe + (size_t)NC*2*DI*DS;     // +73,728 (total < oe size)
            scan_p1<<<dim3(6, 2, NC), 256, 0, stream>>>(dtb, dblb, xcb, Ap, hend, sumdt, NQ, CL, 2, 8);
            scan_p3f<<<dim3(6, 2, NC), 256, 0, stream>>>(dtb, dblb, xcb, xzb, Ap, m_D + (size_t)li*DI,
                                                         hend, sumdt, yb, NQ, CL, 2, 8);
        }
        // mamba out-proj + residual(xn)
        GS(yb, wl + off_out, P_OUT, 768, 768, 384, 4, 1536, 1536, 768, 0, 0, 1);
        EPI(x1s, nullptr, xn, 1, 4, 768, 768, 768, 1536, 0, 0, 768, EPI_ADDT);
        // q projection (partials consumed directly by attn)
        GS(x1s, wl + off_aIn, P_AIN, 768, 768, 192, 4, 1536, 768, 768, 0, 0, 1);
        // k/v: hoisted batched buffer, or per-layer fallback
        const float* kvp;
        if (kvHoist) {
            kvp = kvAll + (size_t)l * 2048 * 1536;
        } else {
            GD(cbuf, wl + off_aIn + 768LL*768, P_AIN, oe, a_in_b + (size_t)l*2304 + 768,
               2048, 1536, 768, 768, 768, 1536, 0,0,0,0, 1, GF_BIAS);
            kvp = oe;
        }
        attn_kernel<<<2*NQ, 64, 0, stream>>>(Cp, a_in_b + (size_t)l*2304, kvp, ob, 4, 768);
        // attn out-proj -> x1s[:,768:]
        GS(ob, wl + off_aOut, P_AOUT, 768, 768, 192, 4, 768, 768, 768, 0, 0, 1);
        EPI(x1s + 768, a_out_b + (size_t)l*768, nullptr, 1, 4, 768, 768, 768, 1536, 0, 0, 0, EPI_BIAS);
        // cross proj: fused LN epilogue -> xn for next layer; plain EPI for last
        GS(x1s, wl + off_cr, P_CR, 768, 768, 384, 4, 1536, 1536, 768, 0, 0, 1);
        if (l == NBK - 1) {
            EPI(out, cr_b + (size_t)l*768, nullptr, 1, 4, 768, 768, 768, 768, 0, 0, 0, EPI_BIAS);
        } else {
            epi_ln_kernel<<<768, 256, 0, stream>>>(Cp, xn, cr_b + (size_t)l*768,
                                                   sn_g + (size_t)(l+1)*768,
                                                   sn_b + (size_t)(l+1)*768,
                                                   4, 768, 768);
        }
    }
}

// Round 6
// 4131.199 us; speedup vs baseline: 1.0372x; 1.0372x over previous
//
#include <hip/hip_runtime.h>
#include <hip/hip_bf16.h>

// ---- model constants ----
#define DIMQ 768
#define D_IN 1024
#define NQ 384
#define NBK 12
#define BATCH 2
#define LSEQ 1024
#define DI 1536
#define DS 16
#define DTR 48
#define NH 16
#define HD 48

typedef __attribute__((ext_vector_type(8))) short short8;
typedef __attribute__((ext_vector_type(4))) float f32x4;

#define GF_BIAS 1
#define GF_SOFTPLUS 2
#define EPI_BIAS 1
#define EPI_ADDT 2

#define LOG2E 1.4426950408889634f

__device__ __forceinline__ unsigned short f2bf(float f) {
    unsigned int u = __builtin_bit_cast(unsigned int, f);
    u = (u + 0x7FFFu + ((u >> 16) & 1u)) >> 16;
    return (unsigned short)u;
}
__device__ __forceinline__ float bf2f(unsigned short h) {
    unsigned int u = ((unsigned int)h) << 16;
    return __builtin_bit_cast(float, u);
}

__device__ __forceinline__ void gload_lds16(const void* g, void* l) {
    __builtin_amdgcn_global_load_lds(
        (const __attribute__((address_space(1))) void*)g,
        (__attribute__((address_space(3))) void*)l, 16, 0, 0);
}

// ---------------------------------------------------------------------------
// Weight conversion: fp32 -> bf16 hi/lo planes, with zero padding.
// ---------------------------------------------------------------------------
struct WTab {
    const float* src[10];
    long long dstOff[10];
    long long ps[10];
    int cum[10];
    int rows[10], cols[10], dcols[10];
    int n;
    int total;
};

__global__ void wconv_kernel(unsigned short* __restrict__ dst, WTab T)
{
    const int i = blockIdx.x * 256 + threadIdx.x;
    if (i >= T.total) return;
    int sI = 0;
    while (i >= T.cum[sI]) ++sI;
    const int e = i - (sI ? T.cum[sI - 1] : 0);
    const int dcols = T.dcols[sI];
    const int r = e / dcols;
    const int c = e - r * dcols;
    float v = 0.f;
    if (r < T.rows[sI] && c < T.cols[sI]) v = T.src[sI][(long long)r * T.cols[sI] + c];
    const unsigned short h = f2bf(v);
    const unsigned short l = f2bf(v - bf2f(h));
    dst[T.dstOff[sI] + e] = h;
    dst[T.dstOff[sI] + T.ps[sI] + e] = l;
}

// Per-layer block-weight conversion; grid = (28800, nLayers).
struct LTab {
    const float* src[7];
    long long srcStride[7], dstOff[7], ps[7];
    int rows[7], cols[7], dcols[7], cum[7];
};

__global__ __launch_bounds__(256)
void wconv_layers(unsigned short* __restrict__ dst, long long layerStride, int lBase, LTab T)
{
    const int e = blockIdx.x * 256 + threadIdx.x;   // < 7,372,800 exactly
    const int l = blockIdx.y + lBase;
    int sI = 0;
    while (e >= T.cum[sI]) ++sI;
    const int eo = e - (sI ? T.cum[sI - 1] : 0);
    const int dc = T.dcols[sI];
    const int r = eo / dc;
    const int c = eo - r * dc;
    float v = 0.f;
    if (r < T.rows[sI] && c < T.cols[sI])
        v = T.src[sI][(long long)l * T.srcStride[sI] + (long long)r * T.cols[sI] + c];
    const unsigned short h = f2bf(v);
    const unsigned short lo2 = f2bf(v - bf2f(h));
    unsigned short* d = dst + (long long)blockIdx.y * layerStride + T.dstOff[sI];
    d[eo] = h;
    d[T.ps[sI] + eo] = lo2;
}

// ---------------------------------------------------------------------------
// GEMM core (double-buffered): C[M,N] = A[M,K](fp32, split in-kernel)
//  * B[N,K]^T (bf16 hi/lo planes via global_load_lds DMA). Tile 64x128, BK=32.
// LDS tiles are XOR-swizzled BOTH-SIDES (16B unit ^= (row>>1)&3): the linear
// gload_lds dest forces the swizzle onto the per-lane GLOBAL src address; the
// ds_read consumer applies the same XOR. Reduces the B-tile ds_read_b128
// conflict from ~8-way to 2-way (free). A-tile (ds_write path) swizzled the
// same way, pad removed.
// NOTE: intra-kernel cross-block reduce (atomic-counter fused split-K) costs a
// per-block buffer_wbl2 on multi-XCD CDNA -> 93us/dispatch. Keep epilogues at
// kernel boundaries.
// ---------------------------------------------------------------------------
__global__ __launch_bounds__(256, 3)
void gemm_direct(const float* __restrict__ Ag, const unsigned short* __restrict__ Bhl,
                 float* __restrict__ Cg, const float* __restrict__ biasg,
                 int M, int N, int K, int lda, int ldb, int ldc,
                 long long sA, long long sB, long long sC, long long sBias,
                 long long planeB, int flags)
{
    __shared__ __align__(16) unsigned short As[2][2][64][32];
    __shared__ __align__(16) unsigned short Bs[2][2][128][32];

    const int z = blockIdx.z;
    const float* A = Ag + (size_t)z * sA;
    const unsigned short* Bhi = Bhl + (size_t)z * sB;
    const unsigned short* Blo = Bhi + planeB;
    float* C = Cg + (size_t)z * sC;

    const int mBase = blockIdx.x * 64;
    const int nBase = blockIdx.y * 128;
    const int tid = threadIdx.x, lane = tid & 63, wave = tid >> 6;
    const int lm = lane & 15, lq = lane >> 4;
    const int wn = wave * 32;
    const int arow = tid >> 2, aq = tid & 3;
    const int brow = lane >> 2;
    const int bcol = ((lane & 3) ^ ((lane >> 3) & 3)) * 8;     // swizzled src unit
    const int aunit = (aq ^ ((arow >> 1) & 3)) * 8;            // swizzled A store unit
    const int funit = (lq ^ ((lm >> 1) & 3)) * 8;              // swizzled fragment unit

    const int ktiles = (K + 31) >> 5;

    auto issueB = [&](int t, int buf) {
#pragma unroll
        for (int cc = 0; cc < 4; ++cc) {
            const int chunk = wave * 4 + cc;
            const int pl = chunk >> 3;
            const int r16 = chunk & 7;
            const unsigned short* bp = pl ? Blo : Bhi;
            const int n = nBase + r16 * 16 + brow;
            gload_lds16(bp + (size_t)n * ldb + t * 32 + bcol, &Bs[buf][pl][r16 * 16][0]);
        }
    };
    auto loadA = [&](int t, float* v) {
        const int col = t * 32 + aq * 8;
        const float* src = A + (size_t)(mBase + arow) * lda + col;
#pragma unroll
        for (int u = 0; u < 2; ++u) {
            float4 t4 = make_float4(0.f, 0.f, 0.f, 0.f);
            if (col + u * 4 < K) t4 = *(const float4*)(src + u * 4);
            v[u*4+0]=t4.x; v[u*4+1]=t4.y; v[u*4+2]=t4.z; v[u*4+3]=t4.w;
        }
    };
    auto writeA = [&](const float* v, int buf) {
        short8 ph, plv;
#pragma unroll
        for (int j = 0; j < 8; ++j) {
            unsigned short h = f2bf(v[j]);
            ph[j] = (short)h;
            plv[j] = (short)f2bf(v[j] - bf2f(h));
        }
        *(short8*)&As[buf][0][arow][aunit] = ph;
        *(short8*)&As[buf][1][arow][aunit] = plv;
    };

    float av[8];
    issueB(0, 0);
    loadA(0, av);
    writeA(av, 0);

    f32x4 acc[4][2] = {};
    for (int t = 0; t < ktiles; ++t) {
        const int buf = t & 1;
        __syncthreads();
        const bool more = (t + 1) < ktiles;
        if (more) { issueB(t + 1, buf ^ 1); loadA(t + 1, av); }
        short8 ah[4], al[4], bh[2], bl[2];
#pragma unroll
        for (int i = 0; i < 4; ++i) {
            ah[i] = *(const short8*)&As[buf][0][16*i + lm][funit];
            al[i] = *(const short8*)&As[buf][1][16*i + lm][funit];
        }
#pragma unroll
        for (int j = 0; j < 2; ++j) {
            bh[j] = *(const short8*)&Bs[buf][0][wn + 16*j + lm][funit];
            bl[j] = *(const short8*)&Bs[buf][1][wn + 16*j + lm][funit];
        }
#pragma unroll
        for (int i = 0; i < 4; ++i)
#pragma unroll
            for (int j = 0; j < 2; ++j) {
                acc[i][j] = __builtin_amdgcn_mfma_f32_16x16x32_bf16(ah[i], bh[j], acc[i][j], 0, 0, 0);
                acc[i][j] = __builtin_amdgcn_mfma_f32_16x16x32_bf16(ah[i], bl[j], acc[i][j], 0, 0, 0);
                acc[i][j] = __builtin_amdgcn_mfma_f32_16x16x32_bf16(al[i], bh[j], acc[i][j], 0, 0, 0);
            }
        if (more) writeA(av, buf ^ 1);
    }

#pragma unroll
    for (int i = 0; i < 4; ++i)
#pragma unroll
        for (int j = 0; j < 2; ++j)
#pragma unroll
            for (int r = 0; r < 4; ++r) {
                const int m = mBase + i*16 + lq*4 + r;
                const int n = nBase + wn + j*16 + lm;
                float v = acc[i][j][r];
                if (flags & GF_BIAS)     v += biasg[(size_t)z * sBias + n];
                if (flags & GF_SOFTPLUS) v = (v > 20.f) ? v : log1pf(expf(v));
                C[(size_t)m * ldc + n] = v;
            }
}

// Split-K variant (double-buffered): grid.z = Z*S; partials Cp[(z*S+s)][M][ldP].
// kLen must be a multiple of 32. Same swizzled LDS scheme as gemm_direct.
__global__ __launch_bounds__(256, 3)
void gemm_splitk(const float* __restrict__ Ag, const unsigned short* __restrict__ Bhl,
                 float* __restrict__ Cp,
                 int M, int kLen, int S, int lda, int ldb, int ldP,
                 long long sA, long long sB, long long planeB)
{
    __shared__ __align__(16) unsigned short As[2][2][64][32];
    __shared__ __align__(16) unsigned short Bs[2][2][128][32];

    const int bz = blockIdx.z;
    const int s = bz % S, z = bz / S;
    const int kOff = s * kLen;
    const float* A = Ag + (size_t)z * sA;
    const unsigned short* Bhi = Bhl + (size_t)z * sB;
    const unsigned short* Blo = Bhi + planeB;

    const int mBase = blockIdx.x * 64;
    const int nBase = blockIdx.y * 128;
    const int tid = threadIdx.x, lane = tid & 63, wave = tid >> 6;
    const int lm = lane & 15, lq = lane >> 4;
    const int wn = wave * 32;
    const int arow = tid >> 2, aq = tid & 3;
    const int brow = lane >> 2;
    const int bcol = ((lane & 3) ^ ((lane >> 3) & 3)) * 8;
    const int aunit = (aq ^ ((arow >> 1) & 3)) * 8;
    const int funit = (lq ^ ((lm >> 1) & 3)) * 8;

    const int ktiles = kLen >> 5;

    auto issueB = [&](int t, int buf) {
#pragma unroll
        for (int cc = 0; cc < 4; ++cc) {
            const int chunk = wave * 4 + cc;
            const int pl = chunk >> 3;
            const int r16 = chunk & 7;
            const unsigned short* bp = pl ? Blo : Bhi;
            const int n = nBase + r16 * 16 + brow;
            gload_lds16(bp + (size_t)n * ldb + kOff + t * 32 + bcol, &Bs[buf][pl][r16 * 16][0]);
        }
    };
    auto loadA = [&](int t, float* v) {
        const float* src = A + (size_t)(mBase + arow) * lda + kOff + t * 32 + aq * 8;
#pragma unroll
        for (int u = 0; u < 2; ++u) {
            const float4 t4 = *(const float4*)(src + u * 4);
            v[u*4+0]=t4.x; v[u*4+1]=t4.y; v[u*4+2]=t4.z; v[u*4+3]=t4.w;
        }
    };
    auto writeA = [&](const float* v, int buf) {
        short8 ph, plv;
#pragma unroll
        for (int j = 0; j < 8; ++j) {
            unsigned short h = f2bf(v[j]);
            ph[j] = (short)h;
            plv[j] = (short)f2bf(v[j] - bf2f(h));
        }
        *(short8*)&As[buf][0][arow][aunit] = ph;
        *(short8*)&As[buf][1][arow][aunit] = plv;
    };

    float av[8];
    issueB(0, 0);
    loadA(0, av);
    writeA(av, 0);

    f32x4 acc[4][2] = {};
    for (int t = 0; t < ktiles; ++t) {
        const int buf = t & 1;
        __syncthreads();
        const bool more = (t + 1) < ktiles;
        if (more) { issueB(t + 1, buf ^ 1); loadA(t + 1, av); }
        short8 ah[4], al[4], bh[2], bl[2];
#pragma unroll
        for (int i = 0; i < 4; ++i) {
            ah[i] = *(const short8*)&As[buf][0][16*i + lm][funit];
            al[i] = *(const short8*)&As[buf][1][16*i + lm][funit];
        }
#pragma unroll
        for (int j = 0; j < 2; ++j) {
            bh[j] = *(const short8*)&Bs[buf][0][wn + 16*j + lm][funit];
            bl[j] = *(const short8*)&Bs[buf][1][wn + 16*j + lm][funit];
        }
#pragma unroll
        for (int i = 0; i < 4; ++i)
#pragma unroll
            for (int j = 0; j < 2; ++j) {
                acc[i][j] = __builtin_amdgcn_mfma_f32_16x16x32_bf16(ah[i], bh[j], acc[i][j], 0, 0, 0);
                acc[i][j] = __builtin_amdgcn_mfma_f32_16x16x32_bf16(ah[i], bl[j], acc[i][j], 0, 0, 0);
                acc[i][j] = __builtin_amdgcn_mfma_f32_16x16x32_bf16(al[i], bh[j], acc[i][j], 0, 0, 0);
            }
        if (more) writeA(av, buf ^ 1);
    }

    float* Cb = Cp + (size_t)bz * M * ldP;
#pragma unroll
    for (int i = 0; i < 4; ++i)
#pragma unroll
        for (int j = 0; j < 2; ++j)
#pragma unroll
            for (int r = 0; r < 4; ++r) {
                const int m = mBase + i*16 + lq*4 + r;
                const int n = nBase + wn + j*16 + lm;
                Cb[(size_t)m * ldP + n] = acc[i][j][r];
            }
}

// Reduce partials + bias/residual, write fp32 out.
__global__ void epi_kernel(const float* __restrict__ Cp, float* __restrict__ outF,
                           const float* __restrict__ bias, const float* __restrict__ addT,
                           int Z, int S, int M, int N, int ldP, int ldOut,
                           long long sOutZ, long long sBiasZ, int ldAdd, int flags)
{
    const int n4 = N >> 2;
    const int idx = blockIdx.x * 256 + threadIdx.x;
    if (idx >= Z * M * n4) return;
    const int c4 = idx % n4;
    const int rem = idx / n4;
    const int m = rem % M;
    const int z = rem / M;
    const int n = c4 * 4;
    const float* base = Cp + ((size_t)z * S * M + m) * ldP + n;
    float4 v = *(const float4*)base;
    for (int s = 1; s < S; ++s) {
        const float4 u = *(const float4*)(base + (size_t)s * M * ldP);
        v.x += u.x; v.y += u.y; v.z += u.z; v.w += u.w;
    }
    if (flags & EPI_BIAS) {
        const float4 b4 = *(const float4*)(bias + (size_t)z * sBiasZ + n);
        v.x += b4.x; v.y += b4.y; v.z += b4.z; v.w += b4.w;
    }
    if (flags & EPI_ADDT) {
        const float4 a4 = *(const float4*)(addT + (size_t)m * ldAdd + n);
        v.x += a4.x; v.y += a4.y; v.z += a4.z; v.w += a4.w;
    }
    *(float4*)(outF + (size_t)z * sOutZ + (size_t)m * ldOut + n) = v;
}

// Reduce partials + bias, then LayerNorm the 768-wide row, write xn.
__global__ __launch_bounds__(256)
void epi_ln_kernel(const float* __restrict__ Cp, float* __restrict__ outF,
                   const float* __restrict__ bias,
                   const float* __restrict__ g, const float* __restrict__ b,
                   int S, int M, int ldP)
{
    const int m = blockIdx.x;
    const int tid = threadIdx.x;
    __shared__ float red[8];
    float v[3];
    float s = 0.f, s2 = 0.f;
#pragma unroll
    for (int j = 0; j < 3; ++j) {
        const int n = tid + j * 256;
        const float* pp = Cp + (size_t)m * ldP + n;
        float x = pp[0];
        for (int q = 1; q < S; ++q) x += pp[(size_t)q * M * ldP];
        x += bias[n];
        v[j] = x; s += x; s2 += x * x;
    }
#pragma unroll
    for (int o = 32; o; o >>= 1) { s += __shfl_xor(s, o); s2 += __shfl_xor(s2, o); }
    const int wv = tid >> 6;
    if ((tid & 63) == 0) { red[wv] = s; red[4 + wv] = s2; }
    __syncthreads();
    s  = red[0] + red[1] + red[2] + red[3];
    s2 = red[4] + red[5] + red[6] + red[7];
    const float mean = s * (1.f/768.f);
    const float var  = s2 * (1.f/768.f) - mean * mean;
    const float inv  = rsqrtf(var + 1e-5f);
#pragma unroll
    for (int j = 0; j < 3; ++j) {
        const int n = tid + j * 256;
        outF[(size_t)m * DIMQ + n] = (v[j] - mean) * inv * g[n] + b[n];
    }
}

// ---------------------------------------------------------------------------
// LayerNorm over last dim 768. One wave per row. srcMod broadcasts src rows.
// ---------------------------------------------------------------------------
__global__ void ln_kernel(const float* __restrict__ in, float* __restrict__ out,
                          const float* __restrict__ g, const float* __restrict__ b,
                          int rows, int srcMod)
{
    const int row = blockIdx.x * 4 + (threadIdx.x >> 6);
    const int lane = threadIdx.x & 63;
    if (row >= rows) return;
    const float* p = in + (size_t)(row % srcMod) * DIMQ;
    float v[12], s = 0.f, s2 = 0.f;
#pragma unroll
    for (int j = 0; j < 12; ++j) {
        v[j] = p[j*64 + lane];
        s += v[j];
        s2 += v[j]*v[j];
    }
#pragma unroll
    for (int o = 32; o; o >>= 1) { s += __shfl_xor(s, o); s2 += __shfl_xor(s2, o); }
    const float mean = s * (1.f/768.f);
    const float var  = s2 * (1.f/768.f) - mean*mean;
    const float inv  = rsqrtf(var + 1e-5f);
    float* q = out + (size_t)row * DIMQ;
#pragma unroll
    for (int j = 0; j < 12; ++j) {
        const int c = j*64 + lane;
        q[c] = (v[j] - mean) * inv * g[c] + b[c];
    }
}

// ---------------------------------------------------------------------------
// Depthwise causal conv1d (DC=4) + silu.
// ---------------------------------------------------------------------------
__global__ void conv_kernel(const float* __restrict__ xz, float* __restrict__ xc,
                            const float* __restrict__ cw, const float* __restrict__ cb,
                            int Bn, int L, int instShift)
{
    const int idx = blockIdx.x * 256 + threadIdx.x;
    const int total = Bn * L * (DI/4);
    if (idx >= total) return;
    const int d4 = idx % (DI/4);
    const int t  = (idx / (DI/4)) % L;
    const int b  = idx / (L * (DI/4));
    const int inst = b >> instShift;
    const int d = d4 * 4;
    const float* base = xz + (size_t)(b * L) * 3072 + d;
    const float4 w0 = *(const float4*)(cw + (size_t)(inst*DI + d + 0) * 4);
    const float4 w1 = *(const float4*)(cw + (size_t)(inst*DI + d + 1) * 4);
    const float4 w2 = *(const float4*)(cw + (size_t)(inst*DI + d + 2) * 4);
    const float4 w3 = *(const float4*)(cw + (size_t)(inst*DI + d + 3) * 4);
    float4 acc = *(const float4*)(cb + (size_t)inst*DI + d);
    float4 xv[4];
#pragma unroll
    for (int j = 0; j < 4; ++j) {
        const int tt = t - 3 + j;
        xv[j] = (tt >= 0) ? *(const float4*)(base + (size_t)tt * 3072) : make_float4(0,0,0,0);
    }
    acc.x += xv[0].x*w0.x + xv[1].x*w0.y + xv[2].x*w0.z + xv[3].x*w0.w;
    acc.y += xv[0].y*w1.x + xv[1].y*w1.y + xv[2].y*w1.z + xv[3].y*w1.w;
    acc.z += xv[0].z*w2.x + xv[1].z*w2.y + xv[2].z*w2.z + xv[3].z*w2.w;
    acc.w += xv[0].w*w3.x + xv[1].w*w3.y + xv[2].w*w3.z + xv[3].w*w3.w;
    float4 o;
    o.x = acc.x / (1.f + expf(-acc.x));
    o.y = acc.y / (1.f + expf(-acc.y));
    o.z = acc.z / (1.f + expf(-acc.z));
    o.w = acc.w / (1.f + expf(-acc.w));
    *(float4*)(xc + (size_t)(b * L + t) * DI + d) = o;
}

// ---------------------------------------------------------------------------
// Chunked selective scan (3 passes). p2 kept SEPARATE: fusing the carry
// replay into p3 is O(NC^2/2) hend re-reads (~650 MB across layers, +130us).
// ---------------------------------------------------------------------------
__global__ __launch_bounds__(256)
void scan_p1(const float* __restrict__ dt, const float* __restrict__ dbl,
             const float* __restrict__ xc, const float* __restrict__ A_log,
             float* __restrict__ hend, float* __restrict__ sumdt,
             int L, int CL, int Bn, int instShift)
{
    const int d = blockIdx.x * 256 + threadIdx.x;
    const int b = blockIdx.y;
    const int c = blockIdx.z;
    const int inst = b >> instShift;
    const float* ap = A_log + ((size_t)inst * DI + d) * DS;
    float A2[16];
#pragma unroll
    for (int s = 0; s < 16; ++s) A2[s] = -expf(ap[s]) * LOG2E;
    float h[16] = {};
    float sd = 0.f;
    const int t0 = c * CL;
    const size_t rowbase = (size_t)b * L;
    for (int t = t0; t < t0 + CL; ++t) {
        const size_t row = rowbase + t;
        const float dtv = dt[row * DI + d];
        const float xcv = xc[row * DI + d];
        float Bv[16];
        *(float4*)(Bv + 0)  = *(const float4*)(dbl + row * 80 + 48);
        *(float4*)(Bv + 4)  = *(const float4*)(dbl + row * 80 + 52);
        *(float4*)(Bv + 8)  = *(const float4*)(dbl + row * 80 + 56);
        *(float4*)(Bv + 12) = *(const float4*)(dbl + row * 80 + 60);
        sd += dtv;
        const float bx = dtv * xcv;
#pragma unroll
        for (int s = 0; s < 16; ++s)
            h[s] = exp2f(dtv * A2[s]) * h[s] + bx * Bv[s];
    }
    float* hp = hend + (((size_t)c * Bn + b) * DI + d) * DS;
#pragma unroll
    for (int s = 0; s < 16; s += 4)
        *(float4*)(hp + s) = make_float4(h[s], h[s+1], h[s+2], h[s+3]);
    sumdt[((size_t)c * Bn + b) * DI + d] = sd;
}

__global__ void scan_p2(const float* __restrict__ hend, const float* __restrict__ sumdt,
                        const float* __restrict__ A_log, float* __restrict__ hstart,
                        int NC, int Bn, int instShift)
{
    const int gid = blockIdx.x * 256 + threadIdx.x;
    const int s = gid & 15;
    const int rem = gid >> 4;
    const int d = rem % DI;
    const int b = rem / DI;
    const int inst = b >> instShift;
    const float A2 = -expf(A_log[((size_t)inst * DI + d) * DS + s]) * LOG2E;
    float carry = 0.f;
    for (int c = 0; c < NC; ++c) {
        const size_t off = (((size_t)c * Bn + b) * DI + d) * DS + s;
        hstart[off] = carry;
        carry = exp2f(A2 * sumdt[((size_t)c * Bn + b) * DI + d]) * carry + hend[off];
    }
}

__global__ __launch_bounds__(256)
void scan_p3(const float* __restrict__ dt, const float* __restrict__ dbl,
             const float* __restrict__ xc, const float* __restrict__ xz,
             const float* __restrict__ A_log, const float* __restrict__ Dp,
             const float* __restrict__ hstart, float* __restrict__ y,
             int L, int CL, int Bn, int instShift)
{
    const int d = blockIdx.x * 256 + threadIdx.x;
    const int b = blockIdx.y;
    const int c = blockIdx.z;
    const int inst = b >> instShift;
    const float* ap = A_log + ((size_t)inst * DI + d) * DS;
    float A2[16];
#pragma unroll
    for (int s = 0; s < 16; ++s) A2[s] = -expf(ap[s]) * LOG2E;
    const float Dd = Dp[(size_t)inst * DI + d];
    float h[16];
    const float* hp = hstart + (((size_t)c * Bn + b) * DI + d) * DS;
#pragma unroll
    for (int s = 0; s < 16; s += 4) {
        const float4 t4 = *(const float4*)(hp + s);
        h[s] = t4.x; h[s+1] = t4.y; h[s+2] = t4.z; h[s+3] = t4.w;
    }
    const int t0 = c * CL;
    const size_t rowbase = (size_t)b * L;
    for (int t = t0; t < t0 + CL; ++t) {
        const size_t row = rowbase + t;
        const float dtv = dt[row * DI + d];
        const float xcv = xc[row * DI + d];
        const float zv  = xz[row * 3072 + DI + d];
        float Bv[16], Cv[16];
        *(float4*)(Bv + 0)  = *(const float4*)(dbl + row * 80 + 48);
        *(float4*)(Bv + 4)  = *(const float4*)(dbl + row * 80 + 52);
        *(float4*)(Bv + 8)  = *(const float4*)(dbl + row * 80 + 56);
        *(float4*)(Bv + 12) = *(const float4*)(dbl + row * 80 + 60);
        *(float4*)(Cv + 0)  = *(const float4*)(dbl + row * 80 + 64);
        *(float4*)(Cv + 4)  = *(const float4*)(dbl + row * 80 + 68);
        *(float4*)(Cv + 8)  = *(const float4*)(dbl + row * 80 + 72);
        *(float4*)(Cv + 12) = *(const float4*)(dbl + row * 80 + 76);
        const float bx = dtv * xcv;
#pragma unroll
        for (int s = 0; s < 16; ++s)
            h[s] = exp2f(dtv * A2[s]) * h[s] + bx * Bv[s];
        float p0 = 0.f, p1 = 0.f, p2 = 0.f, p3 = 0.f;
#pragma unroll
        for (int s = 0; s < 4; ++s) {
            p0 += h[s]      * Cv[s];
            p1 += h[s + 4]  * Cv[s + 4];
            p2 += h[s + 8]  * Cv[s + 8];
            p3 += h[s + 12] * Cv[s + 12];
        }
        const float p = (p0 + p1) + (p2 + p3);
        y[row * DI + d] = (p + Dd * xcv) * (zv / (1.f + expf(-zv)));
    }
}

// ---------------------------------------------------------------------------
// Local-window cross attention (2-3 keys/query). Reads q directly from the
// split-K partial planes (+bias): the q epilogue kernel is fused in.
// ---------------------------------------------------------------------------
__global__ void attn_kernel(const float* __restrict__ qP, const float* __restrict__ qBias,
                            const float* __restrict__ kv, float* __restrict__ o,
                            int S, int ldP)
{
    const int bi = blockIdx.x;
    const int b = bi / NQ, i = bi % NQ;
    const int tid = threadIdx.x;
    const int h = tid >> 2, r = tid & 3;
    int start, len;
    if (i < 256) { start = 3*i; len = 3; } else { start = 2*i + 256; len = 2; }
    const int col0 = h*48 + r*12;
    float qv[12];
#pragma unroll
    for (int u = 0; u < 12; ++u) {
        const int n = col0 + u;
        float x = qP[(size_t)bi * ldP + n];
        for (int s = 1; s < S; ++s) x += qP[((size_t)s * 768 + bi) * ldP + n];
        qv[u] = x + qBias[n];
    }
    float s[3] = {-1e30f, -1e30f, -1e30f};
    for (int j = 0; j < len; ++j) {
        const float* kp = kv + (size_t)(b*LSEQ + start + j) * 1536 + col0;
        float p = 0.f;
#pragma unroll
        for (int u = 0; u < 12; ++u) p += qv[u] * kp[u];
        p += __shfl_xor(p, 1);
        p += __shfl_xor(p, 2);
        s[j] = p * 0.14433756729740644f;
    }
    const float mx = fmaxf(s[0], fmaxf(s[1], s[2]));
    float e[3];
    e[0] = expf(s[0]-mx); e[1] = expf(s[1]-mx); e[2] = expf(s[2]-mx);
    const float inv = 1.f / (e[0] + e[1] + e[2]);
    float ov[12] = {};
    for (int j = 0; j < len; ++j) {
        const float w = e[j] * inv;
        const float* vp = kv + (size_t)(b*LSEQ + start + j) * 1536 + 768 + col0;
#pragma unroll
        for (int u = 0; u < 12; ++u) ov[u] += w * vp[u];
    }
    float* op = o + (size_t)bi * DIMQ + col0;
#pragma unroll
    for (int u = 0; u < 12; ++u) op[u] = ov[u];
}

// ---------------------------------------------------------------------------
// small utility kernels
// ---------------------------------------------------------------------------
__global__ void flip_kernel(float* __restrict__ X2)
{
    const int idx = blockIdx.x * 256 + threadIdx.x;
    if (idx >= 2*1024*192) return;
    const int d4 = idx % 192;
    const int t  = (idx / 192) % 1024;
    const int b  = idx / (192 * 1024);
    const size_t dst = ((size_t)((2+b)*1024 + t)) * DIMQ + d4*4;
    const size_t src = ((size_t)(b*1024 + (1023 - t))) * DIMQ + d4*4;
    *(float4*)(X2 + dst) = *(const float4*)(X2 + src);
}

__global__ void combine_kernel(const float* __restrict__ oe, const float* __restrict__ feats,
                               float* __restrict__ c)
{
    const int idx = blockIdx.x * 256 + threadIdx.x;
    if (idx >= 2*1024*192) return;
    const int d4 = idx % 192;
    const int t  = (idx / 192) % 1024;
    const int b  = idx / (192 * 1024);
    const size_t fw = ((size_t)(b*1024 + t)) * DIMQ + d4*4;
    const size_t bw = ((size_t)((2+b)*1024 + (1023 - t))) * DIMQ + d4*4;
    const float4 a = *(const float4*)(oe + fw);
    const float4 bb = *(const float4*)(oe + bw);
    const float4 f = *(const float4*)(feats + fw);
    float4 o;
    o.x = a.x + bb.x + f.x; o.y = a.y + bb.y + f.y;
    o.z = a.z + bb.z + f.z; o.w = a.w + bb.w + f.w;
    *(float4*)(c + fw) = o;
}

// ---------------------------------------------------------------------------
extern "C" void kernel_launch(void* const* d_in, const int* in_sizes, int n_in,
                              void* d_out, int out_size, void* d_ws, size_t ws_size,
                              hipStream_t stream) {
    const float* img_emb  = (const float*)d_in[0];
    const float* queries  = (const float*)d_in[1];
    const float* vis_w    = (const float*)d_in[2];
    const float* vis_b    = (const float*)d_in[3];
    const float* lnv_g    = (const float*)d_in[4];
    const float* lnv_b    = (const float*)d_in[5];
    const float* m_in_w   = (const float*)d_in[6];
    const float* m_conv_w = (const float*)d_in[7];
    const float* m_conv_b = (const float*)d_in[8];
    const float* m_xp_w   = (const float*)d_in[9];
    const float* m_dt_w   = (const float*)d_in[10];
    const float* m_dt_b   = (const float*)d_in[11];
    const float* m_A_log  = (const float*)d_in[12];
    const float* m_D      = (const float*)d_in[13];
    const float* m_out_w  = (const float*)d_in[14];
    const float* sn_g     = (const float*)d_in[15];
    const float* sn_b     = (const float*)d_in[16];
    const float* a_in_w   = (const float*)d_in[17];
    const float* a_in_b   = (const float*)d_in[18];
    const float* a_out_w  = (const float*)d_in[19];
    const float* a_out_b  = (const float*)d_in[20];
    const float* cr_w     = (const float*)d_in[21];
    const float* cr_b     = (const float*)d_in[22];
    float* out = (float*)d_out;

    float* ws = (float*)d_ws;
    auto alloc = [&](size_t n) { float* p = ws; ws += n; return p; };
    float* X2   = alloc((size_t)4096*768);
    float* xzb  = alloc((size_t)4096*3072);
    float* xcb  = alloc((size_t)4096*1536);
    float* dblb = alloc((size_t)4096*80);
    float* dtb  = alloc((size_t)4096*1536);
    float* yb   = alloc((size_t)4096*1536);
    float* oe   = alloc((size_t)4096*768);     // also scan temps (hend/hstart[/sumdt])
    float* cbuf = alloc((size_t)2048*768);     // also encoder scan sumdt (pre-combine)
    float* xn   = alloc((size_t)768*768);
    float* x1s  = alloc((size_t)768*1536);
    float* ob   = alloc((size_t)768*768);
    float* Cp   = alloc((size_t)2359296);      // split-K partials (dedicated)
    unsigned short* wenc = (unsigned short*)alloc((size_t)16908288/2);

    const long long LAYER_USH = 14745600;      // ushorts per converted layer
    const size_t usedFloats = (size_t)(ws - (float*)d_ws);
    const size_t needFull = (usedFloats + (size_t)12 * (LAYER_USH/2)) * 4;
    const bool bigW = ws_size >= needFull;
    unsigned short* wlayAll = (unsigned short*)ws;   // 12 layers (bigW) or 1 (fallback)

    // batched-kv buffer sits after the 12 converted layers (only if bigW)
    const size_t kvFloats = (size_t)12 * 2048 * 1536;
    const size_t needKV = needFull + kvFloats * 4;
    const bool kvHoist = bigW && ws_size >= needKV;
    float* kvAll = (float*)(wlayAll + (size_t)12 * LAYER_USH);

    const long long P_VIS = 768LL*1024;
    const long long P_IN  = 3072LL*768;
    const long long P_XP  = 128LL*1536;
    const long long P_DT  = 1536LL*64;
    const long long P_OUT = 768LL*1536;
    const long long P_AIN = 2304LL*768;
    const long long P_AOUT= 768LL*768;
    const long long P_CR  = 768LL*1536;
    const long long off_vis   = 0;
    const long long off_encIn = 2*P_VIS;
    const long long off_encXp = off_encIn + 4*P_IN;
    const long long off_encDt = off_encXp + 4*P_XP;
    const long long off_encOut= off_encDt + 4*P_DT;
    const long long off_in  = 0;
    const long long off_xp  = 2*P_IN;
    const long long off_dt  = off_xp + 2*P_XP;
    const long long off_out = off_dt + 2*P_DT;
    const long long off_aIn = off_out + 2*P_OUT;
    const long long off_aOut= off_aIn + 2*P_AIN;
    const long long off_cr  = off_aOut + 2*P_AOUT;

    auto addSeg = [](WTab& T, const float* src, int rows, int cols, int drows, int dcols,
                     long long dstOff) {
        const int k = T.n;
        T.src[k] = src; T.rows[k] = rows; T.cols[k] = cols; T.dcols[k] = dcols;
        T.ps[k] = (long long)drows * dcols;
        T.dstOff[k] = dstOff;
        T.total += drows * dcols;
        T.cum[k] = T.total;
        T.n = k + 1;
    };

    auto GD = [&](const float* A, const unsigned short* Bhl, long long planeB,
                  float* C, const float* bias,
                  int M, int N, int K, int lda, int ldb, int ldc,
                  long long sA, long long sB, long long sC, long long sBias,
                  int Z, int flags) {
        dim3 grid(M/64, N/128, Z);
        gemm_direct<<<grid, 256, 0, stream>>>(A, Bhl, C, bias, M, N, K, lda, ldb, ldc,
                                              sA, sB, sC, sBias, planeB, flags);
    };
    auto GS = [&](const float* A, const unsigned short* Bhl, long long planeB,
                  int M, int Ntile, int kLen, int S, int lda, int ldb, int ldP,
                  long long sA, long long sB, int Z) {
        dim3 grid(M/64, Ntile/128, Z*S);
        gemm_splitk<<<grid, 256, 0, stream>>>(A, Bhl, Cp, M, kLen, S, lda, ldb, ldP,
                                              sA, sB, planeB);
    };
    auto EPI = [&](float* outF, const float* bias, const float* addT,
                   int Z, int S, int M, int N, int ldP, int ldOut,
                   long long sOutZ, long long sBiasZ, int ldAdd, int flags) {
        const int total = Z * M * (N/4);
        epi_kernel<<<(total+255)/256, 256, 0, stream>>>(Cp, outF, bias, addT, Z, S, M, N,
                                                        ldP, ldOut, sOutZ, sBiasZ, ldAdd, flags);
    };

    // ==== encoder weight conversion ====
    {
        WTab T = {}; T.n = 0; T.total = 0;
        addSeg(T, vis_w, 768, 1024, 768, 1024, off_vis);
        addSeg(T, m_in_w,               3072, 768, 3072, 768, off_encIn);
        addSeg(T, m_in_w + 3072*768,    3072, 768, 3072, 768, off_encIn + 2*P_IN);
        addSeg(T, m_xp_w,               80, 1536, 128, 1536, off_encXp);
        addSeg(T, m_xp_w + 80*1536,     80, 1536, 128, 1536, off_encXp + 2*P_XP);
        addSeg(T, m_dt_w,               1536, 48, 1536, 64, off_encDt);
        addSeg(T, m_dt_w + 1536*48,     1536, 48, 1536, 64, off_encDt + 2*P_DT);
        addSeg(T, m_out_w,              768, 1536, 768, 1536, off_encOut);
        addSeg(T, m_out_w + 768*1536,   768, 1536, 768, 1536, off_encOut + 2*P_OUT);
        wconv_kernel<<<(T.total+255)/256, 256, 0, stream>>>(wenc, T);
    }

    // ==== layer weight conversion table (mamba srcs pre-offset by +2 instances) ====
    LTab LT = {};
    {
        auto seg = [&](int k, const float* src, long long srcStride, int rows, int cols,
                       int drows, int dcols, long long dstOff) {
            LT.src[k] = src; LT.srcStride[k] = srcStride;
            LT.rows[k] = rows; LT.cols[k] = cols; LT.dcols[k] = dcols;
            LT.ps[k] = (long long)drows * dcols; LT.dstOff[k] = dstOff;
            LT.cum[k] = (k ? LT.cum[k-1] : 0) + drows * dcols;
        };
        seg(0, m_in_w  + (size_t)2*3072*768, 3072LL*768, 3072, 768, 3072, 768, off_in);
        seg(1, m_xp_w  + (size_t)2*80*1536,  80LL*1536,  80, 1536, 128, 1536, off_xp);
        seg(2, m_dt_w  + (size_t)2*1536*48,  1536LL*48,  1536, 48, 1536, 64, off_dt);
        seg(3, m_out_w + (size_t)2*768*1536, 768LL*1536, 768, 1536, 768, 1536, off_out);
        seg(4, a_in_w,  2304LL*768, 2304, 768, 2304, 768, off_aIn);
        seg(5, a_out_w, 768LL*768,  768, 768, 768, 768, off_aOut);
        seg(6, cr_w,    768LL*1536, 768, 1536, 768, 1536, off_cr);
    }
    if (bigW)
        wconv_layers<<<dim3(28800, 12), 256, 0, stream>>>(wlayAll, LAYER_USH, 0, LT);

    // ==== vision proj + LN + stacked feats ====
    GD(img_emb, wenc + off_vis, P_VIS, oe, vis_b,
       2048, 768, 1024, 1024, 1024, 768, 0,0,0,0, 1, GF_BIAS);
    ln_kernel<<<512, 256, 0, stream>>>(oe, X2, lnv_g, lnv_b, 2048, 2048);
    flip_kernel<<<(2*1024*192 + 255)/256, 256, 0, stream>>>(X2);

    // ==== encoder mambas (fwd + bwd via Z=2) ====
    GD(X2, wenc + off_encIn, P_IN, xzb, nullptr,
       2048, 3072, 768, 768, 768, 3072, 2048LL*768, 2*P_IN, 2048LL*3072, 0, 2, 0);
    conv_kernel<<<(4*1024*384 + 255)/256, 256, 0, stream>>>(xzb, xcb, m_conv_w, m_conv_b, 4, 1024, 1);
    GS(xcb, wenc + off_encXp, P_XP, 2048, 128, 384, 4, 1536, 1536, 128,
       2048LL*1536, 2*P_XP, 2);
    EPI(dblb, nullptr, nullptr, 2, 4, 2048, 80, 128, 80, 2048LL*80, 0, 0, 0);
    GD(dblb, wenc + off_encDt, P_DT, dtb, m_dt_b,
       2048, 1536, 48, 80, 64, 1536, 2048LL*80, 2*P_DT, 2048LL*1536, 1536, 2,
       GF_BIAS | GF_SOFTPLUS);
    {
        const int NC = 16, CL = 64;
        float* hend   = oe;                         // 1,572,864 floats
        float* hstart = oe + (size_t)NC*4*DI*DS;    // +1,572,864 (ends at oe size)
        float* sumdt  = cbuf;                       // cbuf free until combine
        scan_p1<<<dim3(6, 4, NC), 256, 0, stream>>>(dtb, dblb, xcb, m_A_log, hend, sumdt, 1024, CL, 4, 1);
        scan_p2<<<(4*DI*DS)/256, 256, 0, stream>>>(hend, sumdt, m_A_log, hstart, NC, 4, 1);
        scan_p3<<<dim3(6, 4, NC), 256, 0, stream>>>(dtb, dblb, xcb, xzb, m_A_log, m_D, hstart, yb, 1024, CL, 4, 1);
    }
    GD(yb, wenc + off_encOut, P_OUT, oe, nullptr,
       2048, 768, 1536, 1536, 1536, 768, 2048LL*1536, 2*P_OUT, 2048LL*768, 0, 2, 0);
    combine_kernel<<<(2*1024*192 + 255)/256, 256, 0, stream>>>(oe, X2, cbuf);

    // ==== batched k/v projection for ALL layers (input cbuf is layer-invariant) ====
    if (kvHoist)
        GD(cbuf, wlayAll + off_aIn + 768LL*768, P_AIN, kvAll, a_in_b + 768,
           2048, 1536, 768, 768, 768, 1536,
           0, LAYER_USH, 2048LL*1536, 2304, 12, GF_BIAS);

    // ==== initial LN (broadcast queries, layer-0 norm params) ====
    ln_kernel<<<192, 256, 0, stream>>>(queries, xn, sn_g, sn_b, 768, 384);

    // ==== 12 blocks ====
    for (int l = 0; l < NBK; ++l) {
        const int li = l + 2;
        const unsigned short* wl = bigW ? wlayAll + (size_t)l * LAYER_USH : wlayAll;
        if (!bigW)
            wconv_layers<<<dim3(28800, 1), 256, 0, stream>>>((unsigned short*)wlayAll, LAYER_USH, l, LT);

        GD(xn, wl + off_in, P_IN, xzb, nullptr,
           768, 3072, 768, 768, 768, 3072, 0,0,0,0, 1, 0);
        conv_kernel<<<(2*NQ*384 + 255)/256, 256, 0, stream>>>(
            xzb, xcb, m_conv_w + (size_t)li*DI*4, m_conv_b + (size_t)li*DI, 2, NQ, 8);
        GS(xcb, wl + off_xp, P_XP, 768, 128, 96, 16, 1536, 1536, 128, 0, 0, 1);
        EPI(dblb, nullptr, nullptr, 1, 16, 768, 80, 128, 80, 0, 0, 0, 0);
        GD(dblb, wl + off_dt, P_DT, dtb, m_dt_b + (size_t)li*1536,
           768, 1536, 48, 80, 64, 1536, 0,0,0,0, 1, GF_BIAS | GF_SOFTPLUS);
        {
            const int NC = 24, CL = 16;
            const float* Ap = m_A_log + (size_t)li*DI*DS;
            float* hend   = oe;                          // 1,179,648
            float* hstart = oe + (size_t)NC*2*DI*DS;     // +1,179,648
            float* sumdt  = oe + (size_t)2*NC*2*DI*DS;   // +73,728 (total < oe size)
            scan_p1<<<dim3(6, 2, NC), 256, 0, stream>>>(dtb, dblb, xcb, Ap, hend, sumdt, NQ, CL, 2, 8);
            scan_p2<<<(2*DI*DS)/256, 256, 0, stream>>>(hend, sumdt, Ap, hstart, NC, 2, 8);
            scan_p3<<<dim3(6, 2, NC), 256, 0, stream>>>(dtb, dblb, xcb, xzb, Ap, m_D + (size_t)li*DI,
                                                        hstart, yb, NQ, CL, 2, 8);
        }
        // mamba out-proj + residual(xn)
        GS(yb, wl + off_out, P_OUT, 768, 768, 384, 4, 1536, 1536, 768, 0, 0, 1);
        EPI(x1s, nullptr, xn, 1, 4, 768, 768, 768, 1536, 0, 0, 768, EPI_ADDT);
        // q projection (partials consumed directly by attn)
        GS(x1s, wl + off_aIn, P_AIN, 768, 768, 192, 4, 1536, 768, 768, 0, 0, 1);
        // k/v: hoisted batched buffer, or per-layer fallback
        const float* kvp;
        if (kvHoist) {
            kvp = kvAll + (size_t)l * 2048 * 1536;
        } else {
            GD(cbuf, wl + off_aIn + 768LL*768, P_AIN, oe, a_in_b + (size_t)l*2304 + 768,
               2048, 1536, 768, 768, 768, 1536, 0,0,0,0, 1, GF_BIAS);
            kvp = oe;
        }
        attn_kernel<<<2*NQ, 64, 0, stream>>>(Cp, a_in_b + (size_t)l*2304, kvp, ob, 4, 768);
        // attn out-proj -> x1s[:,768:]
        GS(ob, wl + off_aOut, P_AOUT, 768, 768, 192, 4, 768, 768, 768, 0, 0, 1);
        EPI(x1s + 768, a_out_b + (size_t)l*768, nullptr, 1, 4, 768, 768, 768, 1536, 0, 0, 0, EPI_BIAS);
        // cross proj: fused LN epilogue -> xn for next layer; plain EPI for last
        GS(x1s, wl + off_cr, P_CR, 768, 768, 384, 4, 1536, 1536, 768, 0, 0, 1);
        if (l == NBK - 1) {
            EPI(out, cr_b + (size_t)l*768, nullptr, 1, 4, 768, 768, 768, 768, 0, 0, 0, EPI_BIAS);
        } else {
            epi_ln_kernel<<<768, 256, 0, stream>>>(Cp, xn, cr_b + (size_t)l*768,
                                                   sn_g + (size_t)(l+1)*768,
                                                   sn_b + (size_t)(l+1)*768,
                                                   4, 768, 768);
        }
    }
}